// Round 6
// baseline (2661.903 us; speedup 1.0000x reference)
//
#include <hip/hip_runtime.h>

#define NN 500000
#define NE 8000000
#define NG 5000
#define CH 8
#define NCONV 8
#define HID 128
#define BEPS 1e-5f

#define NBLK 1954                            // (NN+255)/256  (node-major blocks)
#define NBLK2 15625                          // NN*CH/256     (thread-per-(node,c) blocks, exact)
#define SCAN_ELEMS 1024
#define NB_SCAN ((NN + SCAN_ELEMS - 1) / SCAN_ELEMS)   // 489

#define NWIN 16                              // dst windows: csr window ~2MB + cursor 125KB << 4MiB L2
#define WIN (NN / NWIN)                      // 31250 nodes per window
#define FCHUNK 8192
#define NCHUNK ((NE + FCHUNK - 1) / FCHUNK)  // 977

static inline size_t alignup(size_t v, size_t a) { return (v + a - 1) / a * a; }

// ---------------- init: zero hist + pooled(f64) ----------------
__global__ void k_init(int* __restrict__ hist, double* __restrict__ pooled) {
    int i = blockIdx.x * 256 + threadIdx.x;
    if (i < NN) hist[i] = 0;
    if (i < NG * CH) pooled[i] = 0.0;
}

// ---------------- windowed in-degree histogram; nt loads keep window in L2 ----------------
__global__ void k_hist(const int* __restrict__ dst, int* __restrict__ hist) {
    int w = blockIdx.x & (NWIN - 1);
    int chunk = blockIdx.x >> 4;
    int lo = w * WIN, hi = lo + WIN;
    int base = chunk * FCHUNK + threadIdx.x;
#pragma unroll
    for (int k = 0; k < FCHUNK / 256; k++) {
        int e = base + k * 256;
        if (e < NE) {
            int d = __builtin_nontemporal_load(dst + e);
            if (d >= lo && d < hi) atomicAdd(&hist[d], 1);
        }
    }
}

// ---------------- scan phase 1: per-block sums ----------------
__global__ void k_scan1(const int* __restrict__ hist, int* __restrict__ bsum) {
    int b = blockIdx.x, tid = threadIdx.x;
    int base = b * SCAN_ELEMS + tid * 4;
    int s = 0;
#pragma unroll
    for (int k = 0; k < 4; k++) { int i = base + k; if (i < NN) s += hist[i]; }
#pragma unroll
    for (int off = 32; off; off >>= 1) s += __shfl_xor(s, off);
    __shared__ int wsum[4];
    if ((tid & 63) == 0) wsum[tid >> 6] = s;
    __syncthreads();
    if (tid == 0) bsum[b] = wsum[0] + wsum[1] + wsum[2] + wsum[3];
}

// ---------------- scan phase 2: exclusive scan of block sums (1 block) ----------------
__global__ void k_scan2(int* __restrict__ bsum) {
    __shared__ int s[512];
    int tid = threadIdx.x;
    int v = (tid < NB_SCAN) ? bsum[tid] : 0;
    s[tid] = v;
    __syncthreads();
    for (int off = 1; off < 512; off <<= 1) {
        int t = (tid >= off) ? s[tid - off] : 0;
        __syncthreads();
        s[tid] += t;
        __syncthreads();
    }
    if (tid < NB_SCAN) bsum[tid] = s[tid] - v;  // exclusive
}

// ---------------- scan phase 3: rowptr/cursor/dinv ----------------
__global__ void k_scan3(const int* __restrict__ hist, const int* __restrict__ bsum,
                        int* __restrict__ rowptr, int* __restrict__ cursor,
                        float* __restrict__ dinv) {
    int b = blockIdx.x, tid = threadIdx.x;
    int base = b * SCAN_ELEMS + tid * 4;
    int v[4]; int t4 = 0;
#pragma unroll
    for (int k = 0; k < 4; k++) { int i = base + k; v[k] = (i < NN) ? hist[i] : 0; t4 += v[k]; }
    int incl = t4;
#pragma unroll
    for (int off = 1; off < 64; off <<= 1) {
        int t = __shfl_up(incl, off);
        if ((tid & 63) >= off) incl += t;
    }
    __shared__ int wtot[4];
    if ((tid & 63) == 63) wtot[tid >> 6] = incl;
    __syncthreads();
    int woff = 0;
#pragma unroll
    for (int w = 0; w < 4; w++) if (w < (tid >> 6)) woff += wtot[w];
    int excl = incl - t4 + woff + bsum[b];
#pragma unroll
    for (int k = 0; k < 4; k++) {
        int i = base + k;
        if (i < NN) {
            rowptr[i] = excl;
            cursor[i] = excl;
            dinv[i] = rsqrtf((float)(v[k] + 1));  // +1 self-loop
            excl += v[k];
            if (i == NN - 1) rowptr[NN] = excl;
        }
    }
}

// ---------------- windowed CSR fill; nt streaming loads, csr lines combine in L2 ----------------
__global__ void k_fill(const int* __restrict__ src, const int* __restrict__ dst,
                       int* __restrict__ cursor, int* __restrict__ csr) {
    int w = blockIdx.x & (NWIN - 1);
    int chunk = blockIdx.x >> 4;
    int lo = w * WIN, hi = lo + WIN;
    int base = chunk * FCHUNK + threadIdx.x;
#pragma unroll
    for (int k = 0; k < FCHUNK / 256; k++) {
        int e = base + k * 256;
        if (e < NE) {
            int d = __builtin_nontemporal_load(dst + e);
            if (d >= lo && d < hi) {
                int pos = atomicAdd(&cursor[d], 1);
                csr[pos] = __builtin_nontemporal_load(src + e);
            }
        }
    }
}

// ---------------- determinize: insertion-sort each node's csr segment ----------------
// csr content per segment is a fixed multiset; sorting makes ORDER input-determined,
// so all downstream f32 summation orders are bit-stable across calls.
__global__ void k_sortseg(const int* __restrict__ rowptr, int* __restrict__ csr) {
    int n = blockIdx.x * 256 + threadIdx.x;
    if (n >= NN) return;
    int beg = rowptr[n], end = rowptr[n + 1];
    for (int j = beg + 1; j < end; j++) {
        int key = csr[j];
        int k = j - 1;
        while (k >= beg && csr[k] > key) { csr[k + 1] = csr[k]; k--; }
        csr[k + 1] = key;
    }
}

// block-level sum/sumsq of v[CH] (node-major layout) -> partial[blk*16+...]
__device__ __forceinline__ void block_stats_accum(const float v[CH], float* __restrict__ partial) {
    __shared__ float ls[4][2 * CH];
    int tid = threadIdx.x;
#pragma unroll
    for (int c = 0; c < CH; c++) {
        float s = v[c], q = v[c] * v[c];
#pragma unroll
        for (int off = 32; off; off >>= 1) {
            s += __shfl_xor(s, off);
            q += __shfl_xor(q, off);
        }
        if ((tid & 63) == 0) {
            ls[tid >> 6][c] = s;
            ls[tid >> 6][CH + c] = q;
        }
    }
    __syncthreads();
    if (tid < 2 * CH)
        partial[(size_t)blockIdx.x * 2 * CH + tid] =
            ls[0][tid] + ls[1][tid] + ls[2][tid] + ls[3][tid];
}

// ---------------- reduce partials -> stats[16] (f64); block b owns slot b ----------------
__global__ void k_rstats(const float* __restrict__ partial, int nblk, double* __restrict__ stats) {
    int slot = blockIdx.x;     // 0..15
    int tid = threadIdx.x;     // 256
    double acc = 0.0;
    for (int j = tid; j < nblk; j += 256) acc += (double)partial[(size_t)j * 16 + slot];
#pragma unroll
    for (int off = 32; off; off >>= 1) acc += __shfl_xor(acc, off);
    __shared__ double ls[4];
    if ((tid & 63) == 0) ls[tid >> 6] = acc;
    __syncthreads();
    if (tid == 0) stats[slot] = ls[0] + ls[1] + ls[2] + ls[3];
}

// ---------------- embed + block stats ----------------
__global__ void k_embed(const int* __restrict__ x, const float* __restrict__ emb,
                        float* __restrict__ h, float* __restrict__ partial) {
    int i = blockIdx.x * 256 + threadIdx.x;
    float v[CH];
    if (i < NN) {
        int t = x[i];
#pragma unroll
        for (int c = 0; c < CH; c++) v[c] = emb[t * CH + c];
        float4* hp = (float4*)(h + (size_t)i * CH);
        hp[0] = make_float4(v[0], v[1], v[2], v[3]);
        hp[1] = make_float4(v[4], v[5], v[6], v[7]);
    } else {
#pragma unroll
        for (int c = 0; c < CH; c++) v[c] = 0.0f;
    }
    block_stats_accum(v, partial);
}

// ---------------- BN + 8x8 linear; writes ONLY hws = dinv[i]*o ----------------
__global__ void k_transform(const float* __restrict__ h, const float* __restrict__ dinv,
                            const double* __restrict__ stats,
                            const float* __restrict__ gamma, const float* __restrict__ beta,
                            const float* __restrict__ W, float* __restrict__ hws) {
    __shared__ float sW[CH * CH], sScale[CH], sShift[CH];
    int tid = threadIdx.x;
    if (tid < CH * CH) sW[tid] = W[tid];
    if (tid < CH) {
        double mu = stats[tid] * (1.0 / NN);
        double var = stats[CH + tid] * (1.0 / NN) - mu * mu;
        float sc = gamma[tid] * rsqrtf((float)var + BEPS);
        sScale[tid] = sc;
        sShift[tid] = beta[tid] - (float)mu * sc;
    }
    __syncthreads();
    int i = blockIdx.x * 256 + tid;
    if (i >= NN) return;
    const float4* hp = (const float4*)(h + (size_t)i * CH);
    float4 h0 = hp[0], h1 = hp[1];
    float hv[CH] = {h0.x, h0.y, h0.z, h0.w, h1.x, h1.y, h1.z, h1.w};
    float hb[CH];
#pragma unroll
    for (int c = 0; c < CH; c++) hb[c] = hv[c] * sScale[c] + sShift[c];
    float d = dinv[i];
    float o[CH];
#pragma unroll
    for (int j = 0; j < CH; j++) {
        float a = 0.0f;
#pragma unroll
        for (int c = 0; c < CH; c++) a += hb[c] * sW[c * CH + j];
        o[j] = a * d;
    }
    float4* hwp = (float4*)(hws + (size_t)i * CH);
    hwp[0] = make_float4(o[0], o[1], o[2], o[3]);
    hwp[1] = make_float4(o[4], o[5], o[6], o[7]);
}

// ---------------- fused gather+residual+bias+selfloop+relu+h_out+stats ----------------
// thread t -> (node = t>>3, c = t&7); grid exact: NN*CH/256 = 15625
__global__ void __launch_bounds__(256) k_gather(const int* __restrict__ rowptr,
                                                const int* __restrict__ csr,
                                                const float* __restrict__ dinv,
                                                const float* __restrict__ hws,
                                                const float* __restrict__ h_in,
                                                const float* __restrict__ bias,
                                                float* __restrict__ h_out,
                                                float* __restrict__ partial) {
    int t = blockIdx.x * 256 + threadIdx.x;
    int node = t >> 3, c = t & 7;
    int beg = rowptr[node], end = rowptr[node + 1];
    float acc = 0.0f;
    int e = beg;
    for (; e + 1 < end; e += 2) {
        int s0 = __builtin_nontemporal_load(csr + e);
        int s1 = __builtin_nontemporal_load(csr + e + 1);
        acc += hws[(size_t)s0 * CH + c] + hws[(size_t)s1 * CH + c];
    }
    if (e < end) acc += hws[(size_t)__builtin_nontemporal_load(csr + e) * CH + c];
    float d = dinv[node];
    float m = hws[(size_t)node * CH + c];               // = o*d
    float val = h_in[t] + bias[c] + (m + acc) * d;      // residual + bias + selfloop + agg
    float v = fmaxf(val, 0.0f);
    h_out[t] = v;
    // per-channel block stats: lanes with same (lane&7) share channel
    float s = v, q = v * v;
#pragma unroll
    for (int off = 8; off < 64; off <<= 1) {
        s += __shfl_xor(s, off);
        q += __shfl_xor(q, off);
    }
    __shared__ float ls[4][2 * CH];
    int lane = threadIdx.x & 63, wid = threadIdx.x >> 6;
    if (lane < CH) { ls[wid][lane] = s; ls[wid][CH + lane] = q; }
    __syncthreads();
    if (threadIdx.x < 2 * CH)
        partial[(size_t)blockIdx.x * 2 * CH + threadIdx.x] =
            ls[0][threadIdx.x] + ls[1][threadIdx.x] + ls[2][threadIdx.x] + ls[3][threadIdx.x];
}

// ---------------- last layer: fused gather + relu + pool (f64 atomics: order-noise << f32 ulp) ----------------
__global__ void __launch_bounds__(256) k_gather_pool(const int* __restrict__ rowptr,
                                                     const int* __restrict__ csr,
                                                     const float* __restrict__ dinv,
                                                     const float* __restrict__ hws,
                                                     const float* __restrict__ h_in,
                                                     const float* __restrict__ bias,
                                                     const int* __restrict__ batch,
                                                     double* __restrict__ pooled) {
    int t = blockIdx.x * 256 + threadIdx.x;
    int node = t >> 3, c = t & 7;
    int beg = rowptr[node], end = rowptr[node + 1];
    float acc = 0.0f;
    int e = beg;
    for (; e + 1 < end; e += 2) {
        int s0 = __builtin_nontemporal_load(csr + e);
        int s1 = __builtin_nontemporal_load(csr + e + 1);
        acc += hws[(size_t)s0 * CH + c] + hws[(size_t)s1 * CH + c];
    }
    if (e < end) acc += hws[(size_t)__builtin_nontemporal_load(csr + e) * CH + c];
    float d = dinv[node];
    float m = hws[(size_t)node * CH + c];
    float val = h_in[t] + bias[c] + (m + acc) * d;
    atomicAdd(&pooled[(size_t)batch[node] * CH + c], (double)fmaxf(val, 0.0f));
}

// ---------------- per-graph MLP ----------------
__global__ void k_mlp(const double* __restrict__ pooled, const float* __restrict__ hid_w,
                      const float* __restrict__ hid_b, const float* __restrict__ out_w,
                      const float* __restrict__ out_b, float* __restrict__ out) {
    int g = blockIdx.x;
    int j = threadIdx.x;  // 128 threads
    __shared__ float sp[CH];
    __shared__ float part[2];
    if (j < CH) sp[j] = (float)pooled[(size_t)g * CH + j];
    __syncthreads();
    float acc = hid_b[j];
#pragma unroll
    for (int c = 0; c < CH; c++) acc += sp[c] * hid_w[c * HID + j];
    acc = fmaxf(acc, 0.0f) * out_w[j];
#pragma unroll
    for (int off = 32; off; off >>= 1) acc += __shfl_xor(acc, off);
    if ((j & 63) == 0) part[j >> 6] = acc;
    __syncthreads();
    if (j == 0) out[g] = part[0] + part[1] + out_b[0];
}

extern "C" void kernel_launch(void* const* d_in, const int* in_sizes, int n_in,
                              void* d_out, int out_size, void* d_ws, size_t ws_size,
                              hipStream_t stream) {
    const int* x = (const int*)d_in[0];
    const int* ei = (const int*)d_in[1];
    const int* srcp = ei;             // edge_index[0]
    const int* dstp = ei + NE;        // edge_index[1]
    const int* batch = (const int*)d_in[2];
    const float* emb = (const float*)d_in[3];
    const float* gamma = (const float*)d_in[4];
    const float* beta = (const float*)d_in[5];
    const float* convw = (const float*)d_in[6];
    const float* convb = (const float*)d_in[7];
    const float* hid_w = (const float*)d_in[8];
    const float* hid_b = (const float*)d_in[9];
    const float* out_w = (const float*)d_in[10];
    const float* out_b = (const float*)d_in[11];
    float* out = (float*)d_out;

    char* ws = (char*)d_ws;
    size_t off = 0;
    int*   hist    = (int*)(ws + off);   off = alignup(off + (size_t)NN * 4, 256);
    int*   cursor  = (int*)(ws + off);   off = alignup(off + (size_t)NN * 4, 256);
    int*   rowptr  = (int*)(ws + off);   off = alignup(off + ((size_t)NN + 1) * 4, 256);
    float* dinv    = (float*)(ws + off); off = alignup(off + (size_t)NN * 4, 256);
    int*   bsum    = (int*)(ws + off);   off = alignup(off + 512 * 4, 256);
    int*   csr     = (int*)(ws + off);   off = alignup(off + (size_t)NE * 4, 256);
    float* hA      = (float*)(ws + off); off = alignup(off + (size_t)NN * CH * 4, 256);
    float* hB      = (float*)(ws + off); off = alignup(off + (size_t)NN * CH * 4, 256);
    float* hws     = (float*)(ws + off); off = alignup(off + (size_t)NN * CH * 4, 256);
    double* pooled = (double*)(ws + off); off = alignup(off + (size_t)NG * CH * 8, 256);
    float* partial = (float*)(ws + off); off = alignup(off + (size_t)NBLK2 * 2 * CH * 4, 256);
    double* stats  = (double*)(ws + off); off += 2 * CH * 8;

    const int B = 256;
    const int gW = NCHUNK * NWIN;

    k_init<<<NBLK, B, 0, stream>>>(hist, pooled);
    k_hist<<<gW, B, 0, stream>>>(dstp, hist);
    k_scan1<<<NB_SCAN, B, 0, stream>>>(hist, bsum);
    k_scan2<<<1, 512, 0, stream>>>(bsum);
    k_scan3<<<NB_SCAN, B, 0, stream>>>(hist, bsum, rowptr, cursor, dinv);
    k_fill<<<gW, B, 0, stream>>>(srcp, dstp, cursor, csr);
    k_sortseg<<<NBLK, B, 0, stream>>>(rowptr, csr);
    k_embed<<<NBLK, B, 0, stream>>>(x, emb, hA, partial);
    k_rstats<<<16, 256, 0, stream>>>(partial, NBLK, stats);

    float* hc = hA;
    float* hn = hB;
    for (int i = 0; i < NCONV; i++) {
        k_transform<<<NBLK, B, 0, stream>>>(hc, dinv, stats, gamma + i * CH, beta + i * CH,
                                            convw + i * CH * CH, hws);
        if (i < NCONV - 1) {
            k_gather<<<NBLK2, B, 0, stream>>>(rowptr, csr, dinv, hws, hc, convb + i * CH,
                                              hn, partial);
            k_rstats<<<16, 256, 0, stream>>>(partial, NBLK2, stats);
            float* tmp = hc; hc = hn; hn = tmp;
        } else {
            k_gather_pool<<<NBLK2, B, 0, stream>>>(rowptr, csr, dinv, hws, hc, convb + i * CH,
                                                   batch, pooled);
        }
    }
    k_mlp<<<NG, HID, 0, stream>>>(pooled, hid_w, hid_b, out_w, out_b, out);
}

// Round 7
// 2255.328 us; speedup vs baseline: 1.1803x; 1.1803x over previous
//
#include <hip/hip_runtime.h>

#define NN 500000
#define NE 8000000
#define NG 5000
#define CH 8
#define NCONV 8
#define HID 128
#define BEPS 1e-5f

#define NBLK 1954                            // (NN+255)/256  (node-major blocks)
#define NBLK2 15625                          // NN*CH/256     (thread-per-(node,c) blocks, exact)
#define SCAN_ELEMS 1024
#define NB_SCAN ((NN + SCAN_ELEMS - 1) / SCAN_ELEMS)   // 489

#define NWIN 8                               // dst windows (one per XCD) — R4's best config
#define WIN (NN / NWIN)                      // 62500 nodes per window
#define FCHUNK 8192
#define NCHUNK ((NE + FCHUNK - 1) / FCHUNK)  // 977

static inline size_t alignup(size_t v, size_t a) { return (v + a - 1) / a * a; }

// ---------------- init: zero hist + pooled(f64) ----------------
__global__ void k_init(int* __restrict__ hist, double* __restrict__ pooled) {
    int i = blockIdx.x * 256 + threadIdx.x;
    if (i < NN) hist[i] = 0;
    if (i < NG * CH) pooled[i] = 0.0;
}

// ---------------- windowed in-degree histogram (NWIN=8, plain loads — R4 config) ----------------
__global__ void k_hist(const int* __restrict__ dst, int* __restrict__ hist) {
    int w = blockIdx.x & (NWIN - 1);
    int chunk = blockIdx.x >> 3;
    int lo = w * WIN, hi = lo + WIN;
    int base = chunk * FCHUNK + threadIdx.x;
#pragma unroll
    for (int k = 0; k < FCHUNK / 256; k++) {
        int e = base + k * 256;
        if (e < NE) {
            int d = dst[e];
            if (d >= lo && d < hi) atomicAdd(&hist[d], 1);
        }
    }
}

// ---------------- scan phase 1: per-block sums ----------------
__global__ void k_scan1(const int* __restrict__ hist, int* __restrict__ bsum) {
    int b = blockIdx.x, tid = threadIdx.x;
    int base = b * SCAN_ELEMS + tid * 4;
    int s = 0;
#pragma unroll
    for (int k = 0; k < 4; k++) { int i = base + k; if (i < NN) s += hist[i]; }
#pragma unroll
    for (int off = 32; off; off >>= 1) s += __shfl_xor(s, off);
    __shared__ int wsum[4];
    if ((tid & 63) == 0) wsum[tid >> 6] = s;
    __syncthreads();
    if (tid == 0) bsum[b] = wsum[0] + wsum[1] + wsum[2] + wsum[3];
}

// ---------------- scan phase 2: exclusive scan of block sums (1 block) ----------------
__global__ void k_scan2(int* __restrict__ bsum) {
    __shared__ int s[512];
    int tid = threadIdx.x;
    int v = (tid < NB_SCAN) ? bsum[tid] : 0;
    s[tid] = v;
    __syncthreads();
    for (int off = 1; off < 512; off <<= 1) {
        int t = (tid >= off) ? s[tid - off] : 0;
        __syncthreads();
        s[tid] += t;
        __syncthreads();
    }
    if (tid < NB_SCAN) bsum[tid] = s[tid] - v;  // exclusive
}

// ---------------- scan phase 3: rowptr/cursor/dinv ----------------
__global__ void k_scan3(const int* __restrict__ hist, const int* __restrict__ bsum,
                        int* __restrict__ rowptr, int* __restrict__ cursor,
                        float* __restrict__ dinv) {
    int b = blockIdx.x, tid = threadIdx.x;
    int base = b * SCAN_ELEMS + tid * 4;
    int v[4]; int t4 = 0;
#pragma unroll
    for (int k = 0; k < 4; k++) { int i = base + k; v[k] = (i < NN) ? hist[i] : 0; t4 += v[k]; }
    int incl = t4;
#pragma unroll
    for (int off = 1; off < 64; off <<= 1) {
        int t = __shfl_up(incl, off);
        if ((tid & 63) >= off) incl += t;
    }
    __shared__ int wtot[4];
    if ((tid & 63) == 63) wtot[tid >> 6] = incl;
    __syncthreads();
    int woff = 0;
#pragma unroll
    for (int w = 0; w < 4; w++) if (w < (tid >> 6)) woff += wtot[w];
    int excl = incl - t4 + woff + bsum[b];
#pragma unroll
    for (int k = 0; k < 4; k++) {
        int i = base + k;
        if (i < NN) {
            rowptr[i] = excl;
            cursor[i] = excl;
            dinv[i] = rsqrtf((float)(v[k] + 1));  // +1 self-loop
            excl += v[k];
            if (i == NN - 1) rowptr[NN] = excl;
        }
    }
}

// ---------------- windowed CSR fill (NWIN=8, plain loads — R4 config) ----------------
// csr ORDER is nondeterministic across calls; downstream sums are f64 (order-insensitive).
__global__ void k_fill(const int* __restrict__ src, const int* __restrict__ dst,
                       int* __restrict__ cursor, int* __restrict__ csr) {
    int w = blockIdx.x & (NWIN - 1);
    int chunk = blockIdx.x >> 3;
    int lo = w * WIN, hi = lo + WIN;
    int base = chunk * FCHUNK + threadIdx.x;
#pragma unroll
    for (int k = 0; k < FCHUNK / 256; k++) {
        int e = base + k * 256;
        if (e < NE) {
            int d = dst[e];
            if (d >= lo && d < hi) {
                int pos = atomicAdd(&cursor[d], 1);
                csr[pos] = src[e];
            }
        }
    }
}

// ---------------- reduce partials -> stats[16] (f64); block b owns slot b ----------------
__global__ void k_rstats(const float* __restrict__ partial, int nblk, double* __restrict__ stats) {
    int slot = blockIdx.x;     // 0..15
    int tid = threadIdx.x;     // 256
    double acc = 0.0;
    for (int j = tid; j < nblk; j += 256) acc += (double)partial[(size_t)j * 16 + slot];
#pragma unroll
    for (int off = 32; off; off >>= 1) acc += __shfl_xor(acc, off);
    __shared__ double ls[4];
    if ((tid & 63) == 0) ls[tid >> 6] = acc;
    __syncthreads();
    if (tid == 0) stats[slot] = ls[0] + ls[1] + ls[2] + ls[3];
}

// block-level sum/sumsq of v[CH] (node-major layout) -> partial[blk*16+...]
__device__ __forceinline__ void block_stats_accum(const float v[CH], float* __restrict__ partial) {
    __shared__ float ls[4][2 * CH];
    int tid = threadIdx.x;
#pragma unroll
    for (int c = 0; c < CH; c++) {
        float s = v[c], q = v[c] * v[c];
#pragma unroll
        for (int off = 32; off; off >>= 1) {
            s += __shfl_xor(s, off);
            q += __shfl_xor(q, off);
        }
        if ((tid & 63) == 0) {
            ls[tid >> 6][c] = s;
            ls[tid >> 6][CH + c] = q;
        }
    }
    __syncthreads();
    if (tid < 2 * CH)
        partial[(size_t)blockIdx.x * 2 * CH + tid] =
            ls[0][tid] + ls[1][tid] + ls[2][tid] + ls[3][tid];
}

// ---------------- embed + block stats ----------------
__global__ void k_embed(const int* __restrict__ x, const float* __restrict__ emb,
                        float* __restrict__ h, float* __restrict__ partial) {
    int i = blockIdx.x * 256 + threadIdx.x;
    float v[CH];
    if (i < NN) {
        int t = x[i];
#pragma unroll
        for (int c = 0; c < CH; c++) v[c] = emb[t * CH + c];
        float4* hp = (float4*)(h + (size_t)i * CH);
        hp[0] = make_float4(v[0], v[1], v[2], v[3]);
        hp[1] = make_float4(v[4], v[5], v[6], v[7]);
    } else {
#pragma unroll
        for (int c = 0; c < CH; c++) v[c] = 0.0f;
    }
    block_stats_accum(v, partial);
}

// ---------------- BN + 8x8 linear; writes ONLY hws = dinv[i]*o ----------------
__global__ void k_transform(const float* __restrict__ h, const float* __restrict__ dinv,
                            const double* __restrict__ stats,
                            const float* __restrict__ gamma, const float* __restrict__ beta,
                            const float* __restrict__ W, float* __restrict__ hws) {
    __shared__ float sW[CH * CH], sScale[CH], sShift[CH];
    int tid = threadIdx.x;
    if (tid < CH * CH) sW[tid] = W[tid];
    if (tid < CH) {
        double mu = stats[tid] * (1.0 / NN);
        double var = stats[CH + tid] * (1.0 / NN) - mu * mu;
        float sc = gamma[tid] * rsqrtf((float)var + BEPS);
        sScale[tid] = sc;
        sShift[tid] = beta[tid] - (float)mu * sc;
    }
    __syncthreads();
    int i = blockIdx.x * 256 + tid;
    if (i >= NN) return;
    const float4* hp = (const float4*)(h + (size_t)i * CH);
    float4 h0 = hp[0], h1 = hp[1];
    float hv[CH] = {h0.x, h0.y, h0.z, h0.w, h1.x, h1.y, h1.z, h1.w};
    float hb[CH];
#pragma unroll
    for (int c = 0; c < CH; c++) hb[c] = hv[c] * sScale[c] + sShift[c];
    float d = dinv[i];
    float o[CH];
#pragma unroll
    for (int j = 0; j < CH; j++) {
        float a = 0.0f;
#pragma unroll
        for (int c = 0; c < CH; c++) a += hb[c] * sW[c * CH + j];
        o[j] = a * d;
    }
    float4* hwp = (float4*)(hws + (size_t)i * CH);
    hwp[0] = make_float4(o[0], o[1], o[2], o[3]);
    hwp[1] = make_float4(o[4], o[5], o[6], o[7]);
}

// ---------------- fused gather (f64 acc: order-insensitive) +residual+bias+selfloop+relu+stats ----
// thread t -> (node = t>>3, c = t&7); grid exact: NN*CH/256 = 15625
__global__ void __launch_bounds__(256) k_gather(const int* __restrict__ rowptr,
                                                const int* __restrict__ csr,
                                                const float* __restrict__ dinv,
                                                const float* __restrict__ hws,
                                                const float* __restrict__ h_in,
                                                const float* __restrict__ bias,
                                                float* __restrict__ h_out,
                                                float* __restrict__ partial) {
    int t = blockIdx.x * 256 + threadIdx.x;
    int node = t >> 3, c = t & 7;
    int beg = rowptr[node], end = rowptr[node + 1];
    double acc = 0.0;
    int e = beg;
    for (; e + 1 < end; e += 2) {
        int s0 = __builtin_nontemporal_load(csr + e);
        int s1 = __builtin_nontemporal_load(csr + e + 1);
        acc += (double)hws[(size_t)s0 * CH + c] + (double)hws[(size_t)s1 * CH + c];
    }
    if (e < end) acc += (double)hws[(size_t)__builtin_nontemporal_load(csr + e) * CH + c];
    float d = dinv[node];
    float m = hws[(size_t)node * CH + c];               // = o*d (self-loop message)
    float val = h_in[t] + bias[c] + (float)((double)m + acc) * d;
    float v = fmaxf(val, 0.0f);
    h_out[t] = v;
    // per-channel block stats: lanes with same (lane&7) share channel
    float s = v, q = v * v;
#pragma unroll
    for (int off = 8; off < 64; off <<= 1) {
        s += __shfl_xor(s, off);
        q += __shfl_xor(q, off);
    }
    __shared__ float ls[4][2 * CH];
    int lane = threadIdx.x & 63, wid = threadIdx.x >> 6;
    if (lane < CH) { ls[wid][lane] = s; ls[wid][CH + lane] = q; }
    __syncthreads();
    if (threadIdx.x < 2 * CH)
        partial[(size_t)blockIdx.x * 2 * CH + threadIdx.x] =
            ls[0][threadIdx.x] + ls[1][threadIdx.x] + ls[2][threadIdx.x] + ls[3][threadIdx.x];
}

// ---------------- last layer: fused gather + relu + pool (all f64: order-insensitive) ----------------
__global__ void __launch_bounds__(256) k_gather_pool(const int* __restrict__ rowptr,
                                                     const int* __restrict__ csr,
                                                     const float* __restrict__ dinv,
                                                     const float* __restrict__ hws,
                                                     const float* __restrict__ h_in,
                                                     const float* __restrict__ bias,
                                                     const int* __restrict__ batch,
                                                     double* __restrict__ pooled) {
    int t = blockIdx.x * 256 + threadIdx.x;
    int node = t >> 3, c = t & 7;
    int beg = rowptr[node], end = rowptr[node + 1];
    double acc = 0.0;
    int e = beg;
    for (; e + 1 < end; e += 2) {
        int s0 = __builtin_nontemporal_load(csr + e);
        int s1 = __builtin_nontemporal_load(csr + e + 1);
        acc += (double)hws[(size_t)s0 * CH + c] + (double)hws[(size_t)s1 * CH + c];
    }
    if (e < end) acc += (double)hws[(size_t)__builtin_nontemporal_load(csr + e) * CH + c];
    float d = dinv[node];
    float m = hws[(size_t)node * CH + c];
    float val = h_in[t] + bias[c] + (float)((double)m + acc) * d;
    atomicAdd(&pooled[(size_t)batch[node] * CH + c], (double)fmaxf(val, 0.0f));
}

// ---------------- per-graph MLP ----------------
__global__ void k_mlp(const double* __restrict__ pooled, const float* __restrict__ hid_w,
                      const float* __restrict__ hid_b, const float* __restrict__ out_w,
                      const float* __restrict__ out_b, float* __restrict__ out) {
    int g = blockIdx.x;
    int j = threadIdx.x;  // 128 threads
    __shared__ float sp[CH];
    __shared__ float part[2];
    if (j < CH) sp[j] = (float)pooled[(size_t)g * CH + j];
    __syncthreads();
    float acc = hid_b[j];
#pragma unroll
    for (int c = 0; c < CH; c++) acc += sp[c] * hid_w[c * HID + j];
    acc = fmaxf(acc, 0.0f) * out_w[j];
#pragma unroll
    for (int off = 32; off; off >>= 1) acc += __shfl_xor(acc, off);
    if ((j & 63) == 0) part[j >> 6] = acc;
    __syncthreads();
    if (j == 0) out[g] = part[0] + part[1] + out_b[0];
}

extern "C" void kernel_launch(void* const* d_in, const int* in_sizes, int n_in,
                              void* d_out, int out_size, void* d_ws, size_t ws_size,
                              hipStream_t stream) {
    const int* x = (const int*)d_in[0];
    const int* ei = (const int*)d_in[1];
    const int* srcp = ei;             // edge_index[0]
    const int* dstp = ei + NE;        // edge_index[1]
    const int* batch = (const int*)d_in[2];
    const float* emb = (const float*)d_in[3];
    const float* gamma = (const float*)d_in[4];
    const float* beta = (const float*)d_in[5];
    const float* convw = (const float*)d_in[6];
    const float* convb = (const float*)d_in[7];
    const float* hid_w = (const float*)d_in[8];
    const float* hid_b = (const float*)d_in[9];
    const float* out_w = (const float*)d_in[10];
    const float* out_b = (const float*)d_in[11];
    float* out = (float*)d_out;

    char* ws = (char*)d_ws;
    size_t off = 0;
    int*   hist    = (int*)(ws + off);   off = alignup(off + (size_t)NN * 4, 256);
    int*   cursor  = (int*)(ws + off);   off = alignup(off + (size_t)NN * 4, 256);
    int*   rowptr  = (int*)(ws + off);   off = alignup(off + ((size_t)NN + 1) * 4, 256);
    float* dinv    = (float*)(ws + off); off = alignup(off + (size_t)NN * 4, 256);
    int*   bsum    = (int*)(ws + off);   off = alignup(off + 512 * 4, 256);
    int*   csr     = (int*)(ws + off);   off = alignup(off + (size_t)NE * 4, 256);
    float* hA      = (float*)(ws + off); off = alignup(off + (size_t)NN * CH * 4, 256);
    float* hB      = (float*)(ws + off); off = alignup(off + (size_t)NN * CH * 4, 256);
    float* hws     = (float*)(ws + off); off = alignup(off + (size_t)NN * CH * 4, 256);
    double* pooled = (double*)(ws + off); off = alignup(off + (size_t)NG * CH * 8, 256);
    float* partial = (float*)(ws + off); off = alignup(off + (size_t)NBLK2 * 2 * CH * 4, 256);
    double* stats  = (double*)(ws + off); off += 2 * CH * 8;

    const int B = 256;
    const int gW = NCHUNK * NWIN;

    k_init<<<NBLK, B, 0, stream>>>(hist, pooled);
    k_hist<<<gW, B, 0, stream>>>(dstp, hist);
    k_scan1<<<NB_SCAN, B, 0, stream>>>(hist, bsum);
    k_scan2<<<1, 512, 0, stream>>>(bsum);
    k_scan3<<<NB_SCAN, B, 0, stream>>>(hist, bsum, rowptr, cursor, dinv);
    k_fill<<<gW, B, 0, stream>>>(srcp, dstp, cursor, csr);
    k_embed<<<NBLK, B, 0, stream>>>(x, emb, hA, partial);
    k_rstats<<<16, 256, 0, stream>>>(partial, NBLK, stats);

    float* hc = hA;
    float* hn = hB;
    for (int i = 0; i < NCONV; i++) {
        k_transform<<<NBLK, B, 0, stream>>>(hc, dinv, stats, gamma + i * CH, beta + i * CH,
                                            convw + i * CH * CH, hws);
        if (i < NCONV - 1) {
            k_gather<<<NBLK2, B, 0, stream>>>(rowptr, csr, dinv, hws, hc, convb + i * CH,
                                              hn, partial);
            k_rstats<<<16, 256, 0, stream>>>(partial, NBLK2, stats);
            float* tmp = hc; hc = hn; hn = tmp;
        } else {
            k_gather_pool<<<NBLK2, B, 0, stream>>>(rowptr, csr, dinv, hws, hc, convb + i * CH,
                                                   batch, pooled);
        }
    }
    k_mlp<<<NG, HID, 0, stream>>>(pooled, hid_w, hid_b, out_w, out_b, out);
}

// Round 8
// 2156.192 us; speedup vs baseline: 1.2345x; 1.0460x over previous
//
#include <hip/hip_runtime.h>

#define NN 500000
#define NE 8000000
#define NG 5000
#define CH 8
#define NCONV 8
#define HID 128
#define BEPS 1e-5f

#define NBLK 1954                            // (NN+255)/256  (node-major blocks)
#define NBLK2 15625                          // NN*CH/256     (thread-per-(node,c) blocks, exact)
#define SCAN_ELEMS 1024
#define NB_SCAN ((NN + SCAN_ELEMS - 1) / SCAN_ELEMS)   // 489

#define NWIN 8                               // dst windows (one per XCD) — R4's best config
#define WIN (NN / NWIN)                      // 62500 nodes per window
#define FCHUNK 8192
#define NCHUNK ((NE + FCHUNK - 1) / FCHUNK)  // 977

static inline size_t alignup(size_t v, size_t a) { return (v + a - 1) / a * a; }

// ---------------- init: zero hist + pooled(f64) ----------------
__global__ void k_init(int* __restrict__ hist, double* __restrict__ pooled) {
    int i = blockIdx.x * 256 + threadIdx.x;
    if (i < NN) hist[i] = 0;
    if (i < NG * CH) pooled[i] = 0.0;
}

// ---------------- windowed in-degree histogram (R4 config) ----------------
__global__ void k_hist(const int* __restrict__ dst, int* __restrict__ hist) {
    int w = blockIdx.x & (NWIN - 1);
    int chunk = blockIdx.x >> 3;
    int lo = w * WIN, hi = lo + WIN;
    int base = chunk * FCHUNK + threadIdx.x;
#pragma unroll
    for (int k = 0; k < FCHUNK / 256; k++) {
        int e = base + k * 256;
        if (e < NE) {
            int d = dst[e];
            if (d >= lo && d < hi) atomicAdd(&hist[d], 1);
        }
    }
}

// ---------------- scan phase 1 ----------------
__global__ void k_scan1(const int* __restrict__ hist, int* __restrict__ bsum) {
    int b = blockIdx.x, tid = threadIdx.x;
    int base = b * SCAN_ELEMS + tid * 4;
    int s = 0;
#pragma unroll
    for (int k = 0; k < 4; k++) { int i = base + k; if (i < NN) s += hist[i]; }
#pragma unroll
    for (int off = 32; off; off >>= 1) s += __shfl_xor(s, off);
    __shared__ int wsum[4];
    if ((tid & 63) == 0) wsum[tid >> 6] = s;
    __syncthreads();
    if (tid == 0) bsum[b] = wsum[0] + wsum[1] + wsum[2] + wsum[3];
}

// ---------------- scan phase 2 (1 block) ----------------
__global__ void k_scan2(int* __restrict__ bsum) {
    __shared__ int s[512];
    int tid = threadIdx.x;
    int v = (tid < NB_SCAN) ? bsum[tid] : 0;
    s[tid] = v;
    __syncthreads();
    for (int off = 1; off < 512; off <<= 1) {
        int t = (tid >= off) ? s[tid - off] : 0;
        __syncthreads();
        s[tid] += t;
        __syncthreads();
    }
    if (tid < NB_SCAN) bsum[tid] = s[tid] - v;  // exclusive
}

// ---------------- scan phase 3: rowptr/cursor/dinv/dsq ----------------
__global__ void k_scan3(const int* __restrict__ hist, const int* __restrict__ bsum,
                        int* __restrict__ rowptr, int* __restrict__ cursor,
                        float* __restrict__ dinv, float* __restrict__ dsq) {
    int b = blockIdx.x, tid = threadIdx.x;
    int base = b * SCAN_ELEMS + tid * 4;
    int v[4]; int t4 = 0;
#pragma unroll
    for (int k = 0; k < 4; k++) { int i = base + k; v[k] = (i < NN) ? hist[i] : 0; t4 += v[k]; }
    int incl = t4;
#pragma unroll
    for (int off = 1; off < 64; off <<= 1) {
        int t = __shfl_up(incl, off);
        if ((tid & 63) >= off) incl += t;
    }
    __shared__ int wtot[4];
    if ((tid & 63) == 63) wtot[tid >> 6] = incl;
    __syncthreads();
    int woff = 0;
#pragma unroll
    for (int w = 0; w < 4; w++) if (w < (tid >> 6)) woff += wtot[w];
    int excl = incl - t4 + woff + bsum[b];
#pragma unroll
    for (int k = 0; k < 4; k++) {
        int i = base + k;
        if (i < NN) {
            rowptr[i] = excl;
            cursor[i] = excl;
            float deg = (float)(v[k] + 1);     // +1 self-loop
            dinv[i] = rsqrtf(deg);
            dsq[i] = sqrtf(deg);
            excl += v[k];
            if (i == NN - 1) rowptr[NN] = excl;
        }
    }
}

// ---------------- windowed CSR fill (R4 config) ----------------
// csr ORDER nondeterministic across calls; all downstream edge sums are f64.
__global__ void k_fill(const int* __restrict__ src, const int* __restrict__ dst,
                       int* __restrict__ cursor, int* __restrict__ csr) {
    int w = blockIdx.x & (NWIN - 1);
    int chunk = blockIdx.x >> 3;
    int lo = w * WIN, hi = lo + WIN;
    int base = chunk * FCHUNK + threadIdx.x;
#pragma unroll
    for (int k = 0; k < FCHUNK / 256; k++) {
        int e = base + k * 256;
        if (e < NE) {
            int d = dst[e];
            if (d >= lo && d < hi) {
                int pos = atomicAdd(&cursor[d], 1);
                csr[pos] = src[e];
            }
        }
    }
}

// ---------------- one-time: S1[n] = sum_{s in N(n)} dinv[s]  (f64 -> deterministic) ----------------
__global__ void k_s1(const int* __restrict__ rowptr, const int* __restrict__ csr,
                     const float* __restrict__ dinv, float* __restrict__ S1) {
    int n = blockIdx.x * 256 + threadIdx.x;
    if (n >= NN) return;
    int beg = rowptr[n], end = rowptr[n + 1];
    double a = 0.0;
    for (int e = beg; e < end; e++) a += (double)dinv[__builtin_nontemporal_load(csr + e)];
    S1[n] = (float)a;
}

// ---------------- reduce partials -> stats[16] (f64); block b owns slot b ----------------
__global__ void k_rstats(const float* __restrict__ partial, int nblk, double* __restrict__ stats) {
    int slot = blockIdx.x;     // 0..15
    int tid = threadIdx.x;     // 256
    double acc = 0.0;
    for (int j = tid; j < nblk; j += 256) acc += (double)partial[(size_t)j * 16 + slot];
#pragma unroll
    for (int off = 32; off; off >>= 1) acc += __shfl_xor(acc, off);
    __shared__ double ls[4];
    if ((tid & 63) == 0) ls[tid >> 6] = acc;
    __syncthreads();
    if (tid == 0) stats[slot] = ls[0] + ls[1] + ls[2] + ls[3];
}

// block-level sum/sumsq of v[CH] (node-major layout) -> partial[blk*16+...]
__device__ __forceinline__ void block_stats_accum(const float v[CH], float* __restrict__ partial) {
    __shared__ float ls[4][2 * CH];
    int tid = threadIdx.x;
#pragma unroll
    for (int c = 0; c < CH; c++) {
        float s = v[c], q = v[c] * v[c];
#pragma unroll
        for (int off = 32; off; off >>= 1) {
            s += __shfl_xor(s, off);
            q += __shfl_xor(q, off);
        }
        if ((tid & 63) == 0) {
            ls[tid >> 6][c] = s;
            ls[tid >> 6][CH + c] = q;
        }
    }
    __syncthreads();
    if (tid < 2 * CH)
        partial[(size_t)blockIdx.x * 2 * CH + tid] =
            ls[0][tid] + ls[1][tid] + ls[2][tid] + ls[3][tid];
}

// ---------------- embed: stats on raw emb, store hsc = dinv * emb ----------------
__global__ void k_embed(const int* __restrict__ x, const float* __restrict__ emb,
                        const float* __restrict__ dinv,
                        float* __restrict__ hsc, float* __restrict__ partial) {
    int i = blockIdx.x * 256 + threadIdx.x;
    float v[CH];
    if (i < NN) {
        int t = x[i];
#pragma unroll
        for (int c = 0; c < CH; c++) v[c] = emb[t * CH + c];
        float d = dinv[i];
        float4* hp = (float4*)(hsc + (size_t)i * CH);
        hp[0] = make_float4(v[0] * d, v[1] * d, v[2] * d, v[3] * d);
        hp[1] = make_float4(v[4] * d, v[5] * d, v[6] * d, v[7] * d);
    } else {
#pragma unroll
        for (int c = 0; c < CH; c++) v[c] = 0.0f;
    }
    block_stats_accum(v, partial);
}

// ================= fused conv layer =================
// thread t -> (node=t>>3, c=t&7). pre[c] = hsc[node][c] + sum_edges hsc[src][c]  (f64)
// o = (pre .* scale + S1tot * shift) @ W   (8x8 via shuffles)
// val = hsc_in[t]*dsq + bias[c] + dinv * o[c];  v = relu(val)
// hsc_out = v * dinv; block stats on v.
__device__ __forceinline__ float conv_val(const int* __restrict__ rowptr,
                                          const int* __restrict__ csr,
                                          const float* __restrict__ dinv,
                                          const float* __restrict__ dsq,
                                          const float* __restrict__ S1,
                                          const float* __restrict__ hsc_in,
                                          const float* sW, const float* sScale,
                                          const float* sShift, const float* sBias,
                                          int t, int node, int c) {
    int beg = rowptr[node], end = rowptr[node + 1];
    double acc0 = 0.0, acc1 = 0.0;
    int e = beg;
    for (; e + 3 < end; e += 4) {
        int s0 = __builtin_nontemporal_load(csr + e);
        int s1 = __builtin_nontemporal_load(csr + e + 1);
        int s2 = __builtin_nontemporal_load(csr + e + 2);
        int s3 = __builtin_nontemporal_load(csr + e + 3);
        acc0 += (double)hsc_in[(size_t)s0 * CH + c] + (double)hsc_in[(size_t)s1 * CH + c];
        acc1 += (double)hsc_in[(size_t)s2 * CH + c] + (double)hsc_in[(size_t)s3 * CH + c];
    }
    for (; e < end; e++)
        acc0 += (double)hsc_in[(size_t)__builtin_nontemporal_load(csr + e) * CH + c];
    float self = hsc_in[t];
    float pre = (float)(acc0 + acc1 + (double)self);
    float d = dinv[node];
    float s1tot = S1[node] + d;
    float pc = pre * sScale[c] + s1tot * sShift[c];
    // 8x8 W multiply: lane c of each 8-lane group -> o[c]
    int base = (threadIdx.x & 63) & ~7;
    float o = 0.0f;
#pragma unroll
    for (int k = 0; k < 8; k++) o += __shfl(pc, base + k) * sW[k * CH + c];
    return self * dsq[node] + sBias[c] + d * o;
}

__device__ __forceinline__ void load_layer_params(const double* __restrict__ stats,
                                                  const float* __restrict__ gamma,
                                                  const float* __restrict__ beta,
                                                  const float* __restrict__ W,
                                                  const float* __restrict__ bias,
                                                  float* sW, float* sScale,
                                                  float* sShift, float* sBias) {
    int tid = threadIdx.x;
    if (tid < CH * CH) sW[tid] = W[tid];
    if (tid < CH) {
        double mu = stats[tid] * (1.0 / NN);
        double var = stats[CH + tid] * (1.0 / NN) - mu * mu;
        float sc = gamma[tid] * rsqrtf((float)var + BEPS);
        sScale[tid] = sc;
        sShift[tid] = beta[tid] - (float)mu * sc;
        sBias[tid] = bias[tid];
    }
    __syncthreads();
}

__global__ void __launch_bounds__(256) k_gconv(const int* __restrict__ rowptr,
                                               const int* __restrict__ csr,
                                               const float* __restrict__ dinv,
                                               const float* __restrict__ dsq,
                                               const float* __restrict__ S1,
                                               const double* __restrict__ stats,
                                               const float* __restrict__ gamma,
                                               const float* __restrict__ beta,
                                               const float* __restrict__ W,
                                               const float* __restrict__ bias,
                                               const float* __restrict__ hsc_in,
                                               float* __restrict__ hsc_out,
                                               float* __restrict__ partial) {
    __shared__ float sW[CH * CH], sScale[CH], sShift[CH], sBias[CH];
    load_layer_params(stats, gamma, beta, W, bias, sW, sScale, sShift, sBias);
    int t = blockIdx.x * 256 + threadIdx.x;
    int node = t >> 3, c = t & 7;
    float val = conv_val(rowptr, csr, dinv, dsq, S1, hsc_in, sW, sScale, sShift, sBias,
                         t, node, c);
    float v = fmaxf(val, 0.0f);
    hsc_out[t] = v * dinv[node];
    // per-channel block stats
    float s = v, q = v * v;
#pragma unroll
    for (int off = 8; off < 64; off <<= 1) {
        s += __shfl_xor(s, off);
        q += __shfl_xor(q, off);
    }
    __shared__ float ls[4][2 * CH];
    int lane = threadIdx.x & 63, wid = threadIdx.x >> 6;
    if (lane < CH) { ls[wid][lane] = s; ls[wid][CH + lane] = q; }
    __syncthreads();
    if (threadIdx.x < 2 * CH)
        partial[(size_t)blockIdx.x * 2 * CH + threadIdx.x] =
            ls[0][threadIdx.x] + ls[1][threadIdx.x] + ls[2][threadIdx.x] + ls[3][threadIdx.x];
}

// ---------------- last layer: fused conv + relu + pool (f64 atomics) ----------------
__global__ void __launch_bounds__(256) k_gpool(const int* __restrict__ rowptr,
                                               const int* __restrict__ csr,
                                               const float* __restrict__ dinv,
                                               const float* __restrict__ dsq,
                                               const float* __restrict__ S1,
                                               const double* __restrict__ stats,
                                               const float* __restrict__ gamma,
                                               const float* __restrict__ beta,
                                               const float* __restrict__ W,
                                               const float* __restrict__ bias,
                                               const float* __restrict__ hsc_in,
                                               const int* __restrict__ batch,
                                               double* __restrict__ pooled) {
    __shared__ float sW[CH * CH], sScale[CH], sShift[CH], sBias[CH];
    load_layer_params(stats, gamma, beta, W, bias, sW, sScale, sShift, sBias);
    int t = blockIdx.x * 256 + threadIdx.x;
    int node = t >> 3, c = t & 7;
    float val = conv_val(rowptr, csr, dinv, dsq, S1, hsc_in, sW, sScale, sShift, sBias,
                         t, node, c);
    atomicAdd(&pooled[(size_t)batch[node] * CH + c], (double)fmaxf(val, 0.0f));
}

// ---------------- per-graph MLP ----------------
__global__ void k_mlp(const double* __restrict__ pooled, const float* __restrict__ hid_w,
                      const float* __restrict__ hid_b, const float* __restrict__ out_w,
                      const float* __restrict__ out_b, float* __restrict__ out) {
    int g = blockIdx.x;
    int j = threadIdx.x;  // 128 threads
    __shared__ float sp[CH];
    __shared__ float part[2];
    if (j < CH) sp[j] = (float)pooled[(size_t)g * CH + j];
    __syncthreads();
    float acc = hid_b[j];
#pragma unroll
    for (int c = 0; c < CH; c++) acc += sp[c] * hid_w[c * HID + j];
    acc = fmaxf(acc, 0.0f) * out_w[j];
#pragma unroll
    for (int off = 32; off; off >>= 1) acc += __shfl_xor(acc, off);
    if ((j & 63) == 0) part[j >> 6] = acc;
    __syncthreads();
    if (j == 0) out[g] = part[0] + part[1] + out_b[0];
}

extern "C" void kernel_launch(void* const* d_in, const int* in_sizes, int n_in,
                              void* d_out, int out_size, void* d_ws, size_t ws_size,
                              hipStream_t stream) {
    const int* x = (const int*)d_in[0];
    const int* ei = (const int*)d_in[1];
    const int* srcp = ei;             // edge_index[0]
    const int* dstp = ei + NE;        // edge_index[1]
    const int* batch = (const int*)d_in[2];
    const float* emb = (const float*)d_in[3];
    const float* gamma = (const float*)d_in[4];
    const float* beta = (const float*)d_in[5];
    const float* convw = (const float*)d_in[6];
    const float* convb = (const float*)d_in[7];
    const float* hid_w = (const float*)d_in[8];
    const float* hid_b = (const float*)d_in[9];
    const float* out_w = (const float*)d_in[10];
    const float* out_b = (const float*)d_in[11];
    float* out = (float*)d_out;

    char* ws = (char*)d_ws;
    size_t off = 0;
    int*   hist    = (int*)(ws + off);   off = alignup(off + (size_t)NN * 4, 256);
    int*   cursor  = (int*)(ws + off);   off = alignup(off + (size_t)NN * 4, 256);
    int*   rowptr  = (int*)(ws + off);   off = alignup(off + ((size_t)NN + 1) * 4, 256);
    float* dinv    = (float*)(ws + off); off = alignup(off + (size_t)NN * 4, 256);
    float* dsq     = (float*)(ws + off); off = alignup(off + (size_t)NN * 4, 256);
    float* S1      = (float*)(ws + off); off = alignup(off + (size_t)NN * 4, 256);
    int*   bsum    = (int*)(ws + off);   off = alignup(off + 512 * 4, 256);
    int*   csr     = (int*)(ws + off);   off = alignup(off + (size_t)NE * 4, 256);
    float* hA      = (float*)(ws + off); off = alignup(off + (size_t)NN * CH * 4, 256);
    float* hB      = (float*)(ws + off); off = alignup(off + (size_t)NN * CH * 4, 256);
    double* pooled = (double*)(ws + off); off = alignup(off + (size_t)NG * CH * 8, 256);
    float* partial = (float*)(ws + off); off = alignup(off + (size_t)NBLK2 * 2 * CH * 4, 256);
    double* stats  = (double*)(ws + off); off += 2 * CH * 8;

    const int B = 256;
    const int gW = NCHUNK * NWIN;

    k_init<<<NBLK, B, 0, stream>>>(hist, pooled);
    k_hist<<<gW, B, 0, stream>>>(dstp, hist);
    k_scan1<<<NB_SCAN, B, 0, stream>>>(hist, bsum);
    k_scan2<<<1, 512, 0, stream>>>(bsum);
    k_scan3<<<NB_SCAN, B, 0, stream>>>(hist, bsum, rowptr, cursor, dinv, dsq);
    k_fill<<<gW, B, 0, stream>>>(srcp, dstp, cursor, csr);
    k_s1<<<NBLK, B, 0, stream>>>(rowptr, csr, dinv, S1);
    k_embed<<<NBLK, B, 0, stream>>>(x, emb, dinv, hA, partial);
    k_rstats<<<16, 256, 0, stream>>>(partial, NBLK, stats);

    float* hc = hA;
    float* hn = hB;
    for (int i = 0; i < NCONV; i++) {
        if (i < NCONV - 1) {
            k_gconv<<<NBLK2, B, 0, stream>>>(rowptr, csr, dinv, dsq, S1, stats,
                                             gamma + i * CH, beta + i * CH,
                                             convw + i * CH * CH, convb + i * CH,
                                             hc, hn, partial);
            k_rstats<<<16, 256, 0, stream>>>(partial, NBLK2, stats);
            float* tmp = hc; hc = hn; hn = tmp;
        } else {
            k_gpool<<<NBLK2, B, 0, stream>>>(rowptr, csr, dinv, dsq, S1, stats,
                                             gamma + i * CH, beta + i * CH,
                                             convw + i * CH * CH, convb + i * CH,
                                             hc, batch, pooled);
        }
    }
    k_mlp<<<NG, HID, 0, stream>>>(pooled, hid_w, hid_b, out_w, out_b, out);
}